// Round 1
// baseline (325.559 us; speedup 1.0000x reference)
//
#include <hip/hip_runtime.h>
#include <hip/hip_bf16.h>

// CellAnnotator: att (spatially-varying 8x8 local conv) + 4x (64x64 MLP + relu + LN) + 64->1 head.
// K0: transpose Ws -> WT bf16 (ws).  K1: att tiles -> bf16 att (ws).  K2: fused MLP via MFMA.

#define HH 768
#define WW 768
#define CC 64
#define HWPX (HH*WW)

typedef __attribute__((ext_vector_type(8))) short short8;
typedef __attribute__((ext_vector_type(4))) float f32x4;

__device__ __forceinline__ ushort f2bf(float f) {
  union { float f; uint u; } c; c.f = f;
  uint u = c.u;
  uint r = u + 0x7fffu + ((u >> 16) & 1u);   // round-to-nearest-even
  return (ushort)(r >> 16);
}

// ---------------- K0: WT[l][co][ci] = bf16(Ws[l][ci][co]) ----------------
__global__ __launch_bounds__(256)
void prep_wt(const float* __restrict__ Ws, ushort* __restrict__ wt_g) {
  const int idx = blockIdx.x * 256 + threadIdx.x;     // 16384 total
  const int l = idx >> 12, co = (idx >> 6) & 63, ci = idx & 63;
  wt_g[idx] = f2bf(Ws[(l << 12) + (ci << 6) + co]);
}

// ---------------- K1: att ----------------
// out[i,j,c] = sum_{di,dj in [0,8)} x[i+di-3, j+dj-3, c] * sigmoid(x[i,j,di*8+dj])
constexpr int TS = 8, HALO = 15, WPAD = 68;

template<bool BF16OUT>
__global__ __launch_bounds__(256)
void att_kernel(const float* __restrict__ x, void* __restrict__ attv) {
  __shared__ __align__(16) float xs[HALO*HALO*CC];   // 57.6 KB  [hr][hc][ch]
  __shared__ __align__(16) float wsm[64*WPAD];       // 17.4 KB  [px][k], pad 68 to stagger banks
  const int tid = threadIdx.x;
  const int ti = (blockIdx.x / (WW/TS)) * TS;
  const int tj = (blockIdx.x % (WW/TS)) * TS;

  // stage halo tile (float4 over channels; 16 lanes cover one pixel's 256B -> coalesced)
  for (int idx = tid; idx < HALO*HALO*16; idx += 256) {
    const int c4 = (idx & 15) << 2;
    const int pc = idx >> 4;
    const int r = pc / HALO, col = pc - r*HALO;
    const int gi = ti + r - 3, gj = tj + col - 3;
    float4 v = make_float4(0.f, 0.f, 0.f, 0.f);
    if ((unsigned)gi < (unsigned)HH && (unsigned)gj < (unsigned)WW)
      v = *reinterpret_cast<const float4*>(x + ((size_t)(gi*WW + gj) << 6) + c4);
    *reinterpret_cast<float4*>(xs + (pc << 6) + c4) = v;
  }
  __syncthreads();

  // weights = sigmoid(center pixel channels), center always in-bounds
  for (int idx = tid; idx < 64*64; idx += 256) {
    const int p = idx >> 6, k = idx & 63;
    const float v = xs[((((p >> 3) + 3)*HALO) + (p & 7) + 3)*CC + k];
    wsm[p*WPAD + k] = 1.f / (1.f + __expf(-v));
  }
  __syncthreads();

  // thread: 4 channels (ch4..ch4+3), 4 pixels in one tile row
  const int ch4 = (tid & 15) << 2;
  const int pg  = tid >> 4;              // 0..15
  const int pr  = pg >> 1;               // tile row 0..7
  const int pc0 = (pg & 1) << 2;         // tile col base 0 or 4
  float4 acc[4];
  #pragma unroll
  for (int t = 0; t < 4; ++t) acc[t] = make_float4(0.f,0.f,0.f,0.f);

  for (int di = 0; di < 8; ++di) {
    float4 xrow[11];                     // sliding window cols pc0..pc0+10
    #pragma unroll
    for (int q = 0; q < 11; ++q)
      xrow[q] = *reinterpret_cast<const float4*>(xs + (((pr + di)*HALO) + pc0 + q)*CC + ch4);
    float wv[4][8];
    #pragma unroll
    for (int t = 0; t < 4; ++t) {
      float4 wa = *reinterpret_cast<const float4*>(wsm + (pg*4 + t)*WPAD + di*8);
      float4 wb = *reinterpret_cast<const float4*>(wsm + (pg*4 + t)*WPAD + di*8 + 4);
      wv[t][0]=wa.x; wv[t][1]=wa.y; wv[t][2]=wa.z; wv[t][3]=wa.w;
      wv[t][4]=wb.x; wv[t][5]=wb.y; wv[t][6]=wb.z; wv[t][7]=wb.w;
    }
    #pragma unroll
    for (int dj = 0; dj < 8; ++dj) {
      #pragma unroll
      for (int t = 0; t < 4; ++t) {
        const float wg = wv[t][dj];
        const float4 xv = xrow[t + dj];
        acc[t].x = fmaf(xv.x, wg, acc[t].x);
        acc[t].y = fmaf(xv.y, wg, acc[t].y);
        acc[t].z = fmaf(xv.z, wg, acc[t].z);
        acc[t].w = fmaf(xv.w, wg, acc[t].w);
      }
    }
  }

  #pragma unroll
  for (int t = 0; t < 4; ++t) {
    const size_t gp = (size_t)(ti + pr)*WW + (tj + pc0 + t);
    if (BF16OUT) {
      ushort4 s;
      s.x = f2bf(acc[t].x); s.y = f2bf(acc[t].y); s.z = f2bf(acc[t].z); s.w = f2bf(acc[t].w);
      *reinterpret_cast<ushort4*>((ushort*)attv + (gp << 6) + ch4) = s;
    } else {
      *reinterpret_cast<float4*>((float*)attv + (gp << 6) + ch4) = acc[t];
    }
  }
}

// ---------------- K2: fused 4-layer MLP + LN + head ----------------
// Wave handles 16 pixels. MFMA 16x16x32 bf16. A and B both packed with the
// SAME assumed slot->k map (kb*32 + (lane>>4)*8 + s), so any HW K-permutation
// cancels. Verified D layout: ch = nb*16 + (lane&15), px = (lane>>4)*4 + reg.
constexpr int WTPAD = 72;  // ushorts per row (144B, 16B-aligned, bank-staggered)

template<bool BF16WS>
__global__ __launch_bounds__(256)
void mlp_kernel(const void* __restrict__ attv, const ushort* __restrict__ wt_g,
                const float* __restrict__ Ws,
                const float* __restrict__ bs, const float* __restrict__ lns,
                const float* __restrict__ lnb, const float* __restrict__ w_out,
                const float* __restrict__ b_out, float* __restrict__ x0_out,
                float* __restrict__ out1) {
  __shared__ __align__(16) ushort wt[4*64*WTPAD];    // 36.9 KB  WT[l][co][ci] bf16
  __shared__ __align__(16) ushort act[4][16*WTPAD];  //  9.2 KB  per-wave activations
  const int tid = threadIdx.x;

  // stage WT into LDS (one 128B row per thread)
  {
    const int r = tid;                       // 0..255 = (layer, co)
    if (BF16WS) {
      const uint4* src = reinterpret_cast<const uint4*>(wt_g + (r << 6));
      #pragma unroll
      for (int q = 0; q < 8; ++q)
        *reinterpret_cast<uint4*>(wt + r*WTPAD + q*8) = src[q];
    } else {
      const int l = r >> 6, co = r & 63;
      for (int ci = 0; ci < 64; ++ci)
        wt[r*WTPAD + ci] = f2bf(Ws[(l << 12) + (ci << 6) + co]);
    }
  }
  __syncthreads();

  const int lane = tid & 63, wid = tid >> 6;
  const int l15 = lane & 15, lg = lane >> 4;
  const int px_base = blockIdx.x * 64 + wid * 16;
  ushort* const myact = act[wid];
  float y[4][4];                            // [reg][nb] current activations (this lane's 16 values)

  #pragma unroll
  for (int layer = 0; layer < 4; ++layer) {
    short8 a0, a1;
    if (layer == 0) {
      if (BF16WS) {
        const ushort* ap = (const ushort*)attv + ((size_t)(px_base + l15) << 6) + lg*8;
        a0 = *reinterpret_cast<const short8*>(ap);
        a1 = *reinterpret_cast<const short8*>(ap + 32);
      } else {
        const float* ap = (const float*)attv + ((size_t)(px_base + l15) << 6) + lg*8;
        #pragma unroll
        for (int i = 0; i < 8; ++i) { a0[i] = (short)f2bf(ap[i]); a1[i] = (short)f2bf(ap[32 + i]); }
      }
    } else {
      const ushort* ap = myact + l15*WTPAD + lg*8;
      a0 = *reinterpret_cast<const short8*>(ap);
      a1 = *reinterpret_cast<const short8*>(ap + 32);
    }

    f32x4 acc[4];
    #pragma unroll
    for (int nb = 0; nb < 4; ++nb) {
      const ushort* bp = wt + (layer*64 + nb*16 + l15)*WTPAD + lg*8;
      short8 b0 = *reinterpret_cast<const short8*>(bp);
      short8 b1 = *reinterpret_cast<const short8*>(bp + 32);
      acc[nb] = {0.f, 0.f, 0.f, 0.f};
      acc[nb] = __builtin_amdgcn_mfma_f32_16x16x32_bf16(a0, b0, acc[nb], 0, 0, 0);
      acc[nb] = __builtin_amdgcn_mfma_f32_16x16x32_bf16(a1, b1, acc[nb], 0, 0, 0);
    }

    // epilogue: bias, relu, LayerNorm over 64 channels (in-lane over nb + shfl over l15)
    float bias[4], sc[4], lb[4];
    #pragma unroll
    for (int nb = 0; nb < 4; ++nb) {
      const int ch = layer*64 + nb*16 + l15;
      bias[nb] = bs[ch]; sc[nb] = lns[ch]; lb[nb] = lnb[ch];
    }
    #pragma unroll
    for (int reg = 0; reg < 4; ++reg) {
      float s = 0.f, ss = 0.f;
      #pragma unroll
      for (int nb = 0; nb < 4; ++nb) {
        float v = acc[nb][reg] + bias[nb];
        v = fmaxf(v, 0.f);
        y[reg][nb] = v;
        s += v; ss += v*v;
      }
      #pragma unroll
      for (int m = 1; m <= 8; m <<= 1) { s += __shfl_xor(s, m, 64); ss += __shfl_xor(ss, m, 64); }
      const float mu  = s * 0.015625f;
      const float var = ss * 0.015625f - mu*mu;
      const float rstd = rsqrtf(var + 1e-6f);
      #pragma unroll
      for (int nb = 0; nb < 4; ++nb)
        y[reg][nb] = (y[reg][nb] - mu) * rstd * sc[nb] + lb[nb];
    }

    if (layer < 3) {
      #pragma unroll
      for (int reg = 0; reg < 4; ++reg)
        #pragma unroll
        for (int nb = 0; nb < 4; ++nb)
          myact[(lg*4 + reg)*WTPAD + nb*16 + l15] = f2bf(y[reg][nb]);
      __syncthreads();   // order act writes before next layer's reads (uniform across waves)
    }
  }

  // final: x0 (f32) + out = x0 @ w_out + b_out
  float wo[4];
  #pragma unroll
  for (int nb = 0; nb < 4; ++nb) wo[nb] = w_out[nb*16 + l15];
  const float b0s = b_out[0];
  #pragma unroll
  for (int reg = 0; reg < 4; ++reg) {
    const size_t pxg = (size_t)px_base + lg*4 + reg;
    #pragma unroll
    for (int nb = 0; nb < 4; ++nb)
      x0_out[(pxg << 6) + nb*16 + l15] = y[reg][nb];
    float part = y[reg][0]*wo[0] + y[reg][1]*wo[1] + y[reg][2]*wo[2] + y[reg][3]*wo[3];
    #pragma unroll
    for (int m = 1; m <= 8; m <<= 1) part += __shfl_xor(part, m, 64);
    if (l15 == 0) out1[pxg] = part + b0s;
  }
}

extern "C" void kernel_launch(void* const* d_in, const int* in_sizes, int n_in,
                              void* d_out, int out_size, void* d_ws, size_t ws_size,
                              hipStream_t stream) {
  const float* x     = (const float*)d_in[0];
  const float* Ws    = (const float*)d_in[1];
  const float* bs    = (const float*)d_in[2];
  const float* lns   = (const float*)d_in[3];
  const float* lnbv  = (const float*)d_in[4];
  const float* w_out = (const float*)d_in[5];
  const float* b_out = (const float*)d_in[6];
  float* x0_out = (float*)d_out;
  float* out1   = x0_out + (size_t)HWPX * CC;

  const size_t need = 65536 + (size_t)HWPX * CC * sizeof(ushort);
  const int ntiles = (HH/TS)*(WW/TS);     // 9216
  if (ws_size >= need) {
    ushort* wt_g = (ushort*)d_ws;
    ushort* att  = (ushort*)((char*)d_ws + 65536);
    prep_wt<<<64, 256, 0, stream>>>(Ws, wt_g);
    att_kernel<true><<<ntiles, 256, 0, stream>>>(x, att);
    mlp_kernel<true><<<HWPX/64, 256, 0, stream>>>(att, wt_g, Ws, bs, lns, lnbv,
                                                  w_out, b_out, x0_out, out1);
  } else {
    // fallback: f32 att written in-place into the x0 region (block-private pixels -> race-free)
    att_kernel<false><<<ntiles, 256, 0, stream>>>(x, x0_out);
    mlp_kernel<false><<<HWPX/64, 256, 0, stream>>>(x0_out, nullptr, Ws, bs, lns, lnbv,
                                                   w_out, b_out, x0_out, out1);
  }
}